// Round 1
// 357.166 us; speedup vs baseline: 1.0068x; 1.0068x over previous
//
#include <hip/hip_runtime.h>
#include <stdint.h>

#define N 4096

// blocked scratch layout: addr = tile*524288 + kt*16384 + c*2048 + r*16
//   tile = row>>7, r = row&127, kt = kbyte>>7, c = (kbyte>>4)&7
#define TILE_BYTES 524288   // 128 rows * 4096 B
#define KT_BYTES   16384    // 8 chunks * 128 rows * 16 B

#define QSCALE 256.0f            // W -> fp8 software scale (per tensor)
#define INV_QQ (1.0f / 65536.0f) // undo QSCALE^2 on S

typedef int v8i __attribute__((ext_vector_type(8)));
typedef float f32x16 __attribute__((ext_vector_type(16)));

union V8 { v8i v; uint4 h[2]; };

__device__ __forceinline__ void gload16(const unsigned char* g, unsigned char* l) {
  __builtin_amdgcn_global_load_lds(
      (const __attribute__((address_space(1))) unsigned int*)g,
      (__attribute__((address_space(3))) unsigned int*)l, 16, 0, 0);
}

// pack 4 floats -> 4 fp8 e4m3 bytes (OCP on gfx950)
__device__ __forceinline__ int pack4_fp8(float a, float b, float c, float d) {
  int r = __builtin_amdgcn_cvt_pk_fp8_f32(a, b, 0, false);
  r = __builtin_amdgcn_cvt_pk_fp8_f32(c, d, r, true);
  return r;
}

// ---- K1: W1 fp32 [k][j] -> fp8 W1T blocked  +  tvec[k] += W1[k][:] . center ----
// LDS-atomic contention removed: 16-lane shfl reduce, one plain store per row.
__global__ __launch_bounds__(256) void prep_w1(const float* __restrict__ W1,
                                               const float* __restrict__ lb0,
                                               const float* __restrict__ ub0,
                                               unsigned char* __restrict__ W1T,
                                               float* __restrict__ tvec) {
  __shared__ float tile[64 * 65];
  __shared__ float tdot[64];
  const int t = threadIdx.x;
  const int j0 = blockIdx.x * 64, k0 = blockIdx.y * 64;
#pragma unroll
  for (int s = 0; s < 4; ++s) {
    int ck = s * 256 + t;
    int row = ck >> 4;             // k_local 0..63
    int col = (ck & 15) * 4;       // j_local
    float4 v = *(const float4*)(W1 + (size_t)(k0 + row) * N + j0 + col);
    float4 l = *(const float4*)(lb0 + j0 + col);
    float4 u = *(const float4*)(ub0 + j0 + col);
    float part = v.x * 0.5f * (l.x + u.x) + v.y * 0.5f * (l.y + u.y)
               + v.z * 0.5f * (l.z + u.z) + v.w * 0.5f * (l.w + u.w);
    // reduce across the 16 consecutive lanes sharing this row
    part += __shfl_xor(part, 1, 64);
    part += __shfl_xor(part, 2, 64);
    part += __shfl_xor(part, 4, 64);
    part += __shfl_xor(part, 8, 64);
    if ((t & 15) == 0) tdot[row] = part;   // each row written exactly once
    float* d = &tile[row * 65 + col];
    d[0] = v.x; d[1] = v.y; d[2] = v.z; d[3] = v.w;
  }
  __syncthreads();
  if (t < 64) atomicAdd(&tvec[k0 + t], tdot[t]);
  int jl = t >> 2, ch = (t & 3) * 16;   // 16 consecutive k per thread
  float f[16];
#pragma unroll
  for (int m = 0; m < 16; ++m) f[m] = tile[(ch + m) * 65 + jl] * QSCALE;
  uint4 o;
  o.x = (unsigned)pack4_fp8(f[0], f[1], f[2], f[3]);
  o.y = (unsigned)pack4_fp8(f[4], f[5], f[6], f[7]);
  o.z = (unsigned)pack4_fp8(f[8], f[9], f[10], f[11]);
  o.w = (unsigned)pack4_fp8(f[12], f[13], f[14], f[15]);
  int j = j0 + jl;
  int kb = k0 + ch;                     // k byte index
  *(uint4*)(W1T + (size_t)(j >> 7) * TILE_BYTES + (size_t)(kb >> 7) * KT_BYTES
            + (size_t)((kb >> 4) & 7) * 2048 + (j & 127) * 16) = o;
}

// ---- K2: W2 -> fp8 blocked (coalesced panel writes),
//          cvec[i] += b1 . W2[i,:],  Sc[i] += tvec . W2[i,:]  (per 128-k panel) ----
__global__ __launch_bounds__(256) void convert_w2(const float* __restrict__ W2,
                                                  const float* __restrict__ b1,
                                                  const float* __restrict__ tvec,
                                                  unsigned char* __restrict__ W2q,
                                                  float* __restrict__ cvec,
                                                  float* __restrict__ Sc) {
  const int t = threadIdx.x;
  const int i0 = blockIdx.y * 128;       // row tile
  const int k0 = blockIdx.x * 128;       // k panel
  const int r = t & 127;                 // row within tile
  const int h = t >> 7;                  // 0/1: chunk parity
  unsigned char* panel = W2q + (size_t)blockIdx.y * TILE_BYTES
                       + (size_t)blockIdx.x * KT_BYTES;
  float dotb = 0.f, dott = 0.f;
#pragma unroll
  for (int q = 0; q < 4; ++q) {
    int c = 2 * q + h;                   // 16-B k-chunk index 0..7
    const float* p = W2 + (size_t)(i0 + r) * N + k0 + c * 16;
    alignas(16) int packed[4];
#pragma unroll
    for (int m = 0; m < 4; ++m) {
      float4 w = *(const float4*)(p + m * 4);
      float4 b = *(const float4*)(b1 + k0 + c * 16 + m * 4);
      float4 tv = *(const float4*)(tvec + k0 + c * 16 + m * 4);
      dotb += w.x * b.x + w.y * b.y + w.z * b.z + w.w * b.w;
      dott += w.x * tv.x + w.y * tv.y + w.z * tv.z + w.w * tv.w;
      packed[m] = pack4_fp8(w.x * QSCALE, w.y * QSCALE, w.z * QSCALE, w.w * QSCALE);
    }
    // consecutive lanes -> consecutive r -> contiguous 16-B stores
    *(uint4*)(panel + (size_t)c * 2048 + r * 16) = *(const uint4*)packed;
  }
  __shared__ float redb[256], redt[256];
  redb[t] = dotb;
  redt[t] = dott;
  __syncthreads();
  if (t < 128) {
    float vb = redb[t] + redb[t + 128];
    float vt = redt[t] + redt[t + 128];
    atomicAdd(&cvec[i0 + t], vb);
    atomicAdd(&Sc[i0 + t], vt);
  }
}

// ---- K3: R_i = sum_j |(W2q @ W1Tq^T)_ij| * eps_j  via MX fp8 MFMA 32x32x64 ----
// 256x256 block, 512 threads (8 waves, 2x4), per-wave 128x64 = acc[4][2].
// 8-phase-style pipeline: 4 LDS k-half groups (32 KB each, 128 KB total),
// phase = {stage group P+2 (4 gload16); s_waitcnt vmcnt(8) counted; s_barrier;
//          12x ds_read_b128; setprio(1); 8x mfma_scale; setprio(0)}.
// Loads stay in flight across barriers (T3+T4); setprio arbitrates (T5).
// Overwrite target of any stage is >=1 barrier behind its last reader.
#define NT 32   // K tiles of 128 bytes
__global__ __launch_bounds__(512, 2) void gemm_absrow(const unsigned char* __restrict__ A,  // W2q blocked
                                                      const unsigned char* __restrict__ B,  // W1Tq blocked
                                                      const float* __restrict__ lb0,
                                                      const float* __restrict__ ub0,
                                                      float* __restrict__ R_acc) {
  __shared__ __align__(16) unsigned char sm[4 * 32768];   // 128 KB, 4 k-half groups
  const int t = threadIdx.x;                // 0..511
  const int lane = t & 63, w = t >> 6;      // 8 waves
  const int wr = w >> 2, wc = w & 3;        // 2 x 4 wave grid
  const int l31 = lane & 31, half = lane >> 5;

  // bijective XCD swizzle (256 blocks, 256 % 8 == 0)
  const int bid = blockIdx.y * 16 + blockIdx.x;
  const int swz = (bid & 7) * 32 + (bid >> 3);
  const int bm = swz >> 4, bn = swz & 15;
  const int i0 = bm * 256, j0 = bn * 256;

  const unsigned char* gA0 = A + (size_t)(2 * bm) * TILE_BYTES + t * 16;
  const unsigned char* gA1 = gA0 + TILE_BYTES;
  const unsigned char* gB0 = B + (size_t)(2 * bn) * TILE_BYTES + t * 16;
  const unsigned char* gB1 = gB0 + TILE_BYTES;

  f32x16 acc[4][2] = {};
  const int sc1 = 0x7F7F7F7F;  // E8M0 scale = 1.0 in all 4 bytes

  // stage tile kt, k-half h -> group ((kt&1)<<1)|h : A lo/hi then B lo/hi
  auto stage = [&](int kt, int h) {
    const int g = ((kt & 1) << 1) | h;
    unsigned char* d = sm + g * 32768 + t * 16;
    const size_t off = (size_t)kt * KT_BYTES + (size_t)h * 8192;
    gload16(gA0 + off, d);
    gload16(gA1 + off, d + 8192);
    gload16(gB0 + off, d + 16384);
    gload16(gB1 + off, d + 24576);
  };

  auto compute = [&](int kt, int h) {
    const unsigned char* base = sm + (((kt & 1) << 1) | h) * 32768;
    V8 af[4], bf[2];
    const unsigned char* pa = base + wr * 8192 + (half * 2) * 2048 + l31 * 16;
#pragma unroll
    for (int tm = 0; tm < 4; ++tm) {
      const unsigned char* p = pa + tm * 512;          // 32 rows * 16 B
      af[tm].h[0] = *(const uint4*)p;
      af[tm].h[1] = *(const uint4*)(p + 2048);          // next 16-B k-chunk
    }
#pragma unroll
    for (int tn = 0; tn < 2; ++tn) {
      const int j = wc * 64 + tn * 32 + l31;            // col within 256 block
      const unsigned char* p = base + 16384 + (j >> 7) * 8192
                             + (half * 2) * 2048 + (j & 127) * 16;
      bf[tn].h[0] = *(const uint4*)p;
      bf[tn].h[1] = *(const uint4*)(p + 2048);
    }
    __builtin_amdgcn_s_setprio(1);
#pragma unroll
    for (int tm = 0; tm < 4; ++tm)
#pragma unroll
      for (int tn = 0; tn < 2; ++tn)
        acc[tm][tn] = __builtin_amdgcn_mfma_scale_f32_32x32x64_f8f6f4(
            af[tm].v, bf[tn].v, acc[tm][tn],
            0 /*cbsz: fp8*/, 0 /*blgp: fp8*/,
            0, sc1, 0, sc1);
    __builtin_amdgcn_s_setprio(0);
  };

  // prologue: groups G0, G1 (tile 0, both halves)
  stage(0, 0);
  stage(0, 1);

  for (int kt = 0; kt < NT - 1; ++kt) {
#pragma unroll
    for (int h = 0; h < 2; ++h) {
      stage(kt + 1, h);                                  // group P+2
      asm volatile("s_waitcnt vmcnt(8)" ::: "memory");   // group P landed (counted)
      __builtin_amdgcn_s_barrier();                      // all waves' P landed
      asm volatile("" ::: "memory");
      compute(kt, h);
    }
  }
  // tail: kt = NT-1, nothing left to stage
  asm volatile("s_waitcnt vmcnt(4)" ::: "memory");
  __builtin_amdgcn_s_barrier();
  asm volatile("" ::: "memory");
  compute(NT - 1, 0);
  asm volatile("s_waitcnt vmcnt(0)" ::: "memory");
  __builtin_amdgcn_s_barrier();
  asm volatile("" ::: "memory");
  compute(NT - 1, 1);

  // epilogue: eps-weighted row L1 norm. C/D 32x32 layout:
  // col = lane&31, row = (r&3) + 8*(r>>2) + 4*(lane>>5)
  float epsv[2];
#pragma unroll
  for (int tn = 0; tn < 2; ++tn) {
    int j = j0 + wc * 64 + tn * 32 + l31;
    epsv[tn] = 0.5f * (ub0[j] - lb0[j]);
  }
#pragma unroll
  for (int tm = 0; tm < 4; ++tm) {
#pragma unroll
    for (int r = 0; r < 16; ++r) {
      float s = fabsf(acc[tm][0][r]) * epsv[0] + fabsf(acc[tm][1][r]) * epsv[1];
#pragma unroll
      for (int off = 1; off < 32; off <<= 1)   // reduce within each 32-lane half
        s += __shfl_xor(s, off, 64);
      if (l31 == 0) {
        int i = i0 + wr * 128 + tm * 32 + (r & 3) + 8 * (r >> 2) + 4 * half;
        atomicAdd(&R_acc[i], s);
      }
    }
  }
}

// ---- K4: fused zero-fill + DeepPolyReLU patch (single pass over 134 MB) ----
struct ReluVals { float lslope, uslope, uinter; };

__device__ __forceinline__ ReluVals relu_vals(int i,
                                              const float* __restrict__ cvec,
                                              const float* __restrict__ Sc,
                                              const float* __restrict__ b2,
                                              const float* __restrict__ R_acc,
                                              const float* __restrict__ raw_alpha) {
  float mid = Sc[i] + cvec[i] + b2[i];
  float rr = R_acc[i] * INV_QQ;
  float lb = mid - rr;
  float ub = mid + rr;
  float alpha = 1.f / (1.f + expf(-raw_alpha[i]));
  float denom = ub - lb;
  float slope = (denom == 0.f) ? 0.f : ub / denom;
  bool below = ub <= 0.f, above = lb >= 0.f;
  bool crossing = !(below || above);
  float base = above ? 1.f : 0.f;
  ReluVals v;
  v.uslope = crossing ? slope : base;
  v.uinter = crossing ? (1.f - slope) * ub : 0.f;
  float l1 = crossing ? 0.f : base;
  float l2 = crossing ? 1.f : base;
  v.lslope = alpha * l1 + (1.f - alpha) * l2;
  return v;
}

__global__ __launch_bounds__(256) void fill_patch(float4* __restrict__ out, int n4,
                                                  const float* __restrict__ cvec,
                                                  const float* __restrict__ Sc,
                                                  const float* __restrict__ b2,
                                                  const float* __restrict__ R_acc,
                                                  const float* __restrict__ raw_alpha) {
  const size_t NN = (size_t)N * N;
  const size_t d1_end = NN;              // diag(lslope)
  const size_t d2_beg = NN + N;          // diag(uslope) after lintercept zeros
  const size_t d2_end = 2 * NN + N;      // uintercept tail
  int idx = blockIdx.x * 256 + threadIdx.x;
  int stride = gridDim.x * 256;
  for (int i = idx; i < n4; i += stride) {
    size_t e = 4 * (size_t)i;
    float4 v = make_float4(0.f, 0.f, 0.f, 0.f);
    if (e >= d2_end) {
      int b = (int)(e - d2_end);
      v.x = relu_vals(b + 0, cvec, Sc, b2, R_acc, raw_alpha).uinter;
      v.y = relu_vals(b + 1, cvec, Sc, b2, R_acc, raw_alpha).uinter;
      v.z = relu_vals(b + 2, cvec, Sc, b2, R_acc, raw_alpha).uinter;
      v.w = relu_vals(b + 3, cvec, Sc, b2, R_acc, raw_alpha).uinter;
    } else if (e < d1_end) {
      int r = (int)(e >> 12), c = (int)(e & 4095);
      if (r >= c && r < c + 4)
        (&v.x)[r - c] = relu_vals(r, cvec, Sc, b2, R_acc, raw_alpha).lslope;
    } else if (e >= d2_beg) {
      size_t e2 = e - d2_beg;
      int r = (int)(e2 >> 12), c = (int)(e2 & 4095);
      if (r >= c && r < c + 4)
        (&v.x)[r - c] = relu_vals(r, cvec, Sc, b2, R_acc, raw_alpha).uslope;
    }
    out[i] = v;
  }
}

extern "C" void kernel_launch(void* const* d_in, const int* in_sizes, int n_in,
                              void* d_out, int out_size, void* d_ws, size_t ws_size,
                              hipStream_t stream) {
  const float* raw_alpha = (const float*)d_in[0];
  const float* lb0 = (const float*)d_in[1];
  const float* ub0 = (const float*)d_in[2];
  const float* W1 = (const float*)d_in[3];
  const float* b1 = (const float*)d_in[4];
  const float* W2 = (const float*)d_in[5];
  const float* b2 = (const float*)d_in[6];

  float* tvec = (float*)d_ws;        // [N]  W1 @ center         (atomic-accum)
  float* cvec = tvec + N;            // [N]  b1 @ W2^T           (atomic-accum)
  float* Sc = cvec + N;              // [N]  W2 @ tvec           (atomic-accum)
  float* R_acc = Sc + N;             // [N]  eps-weighted row L1 (atomic-accum)

  // d_out (134 MB) doubles as fp8 blocked scratch until the final fill
  unsigned char* W2q = (unsigned char*)d_out;        // [N*N] fp8 blocked, 16 MB
  unsigned char* W1Tq = W2q + (size_t)N * N;         // [N*N] fp8 blocked, 16 MB

  (void)hipMemsetAsync(d_ws, 0, 4 * N * sizeof(float), stream);
  prep_w1<<<dim3(N / 64, N / 64), 256, 0, stream>>>(W1, lb0, ub0, W1Tq, tvec);
  convert_w2<<<dim3(N / 128, N / 128), 256, 0, stream>>>(W2, b1, tvec, W2q, cvec, Sc);
  gemm_absrow<<<dim3(16, 16), 512, 0, stream>>>(W2q, W1Tq, lb0, ub0, R_acc);
  int n4 = out_size / 4;
  fill_patch<<<8192, 256, 0, stream>>>((float4*)d_out, n4, cvec, Sc, b2, R_acc, raw_alpha);
}

// Round 2
// 354.512 us; speedup vs baseline: 1.0143x; 1.0075x over previous
//
#include <hip/hip_runtime.h>
#include <stdint.h>

#define N 4096

// blocked scratch layout: addr = tile*524288 + kt*16384 + c*2048 + r*16
//   tile = row>>7, r = row&127, kt = kbyte>>7, c = (kbyte>>4)&7
#define TILE_BYTES 524288   // 128 rows * 4096 B
#define KT_BYTES   16384    // 8 chunks * 128 rows * 16 B

#define QSCALE 256.0f            // W -> fp8 software scale (per tensor)
#define INV_QQ (1.0f / 65536.0f) // undo QSCALE^2 on S

typedef int v8i __attribute__((ext_vector_type(8)));
typedef float f32x16 __attribute__((ext_vector_type(16)));
typedef unsigned int u32x4 __attribute__((ext_vector_type(4)));
typedef float f32x4 __attribute__((ext_vector_type(4)));

union V8 { v8i v; u32x4 h[2]; };

__device__ __forceinline__ void gload16(const unsigned char* g, unsigned char* l) {
  __builtin_amdgcn_global_load_lds(
      (const __attribute__((address_space(1))) unsigned int*)g,
      (__attribute__((address_space(3))) unsigned int*)l, 16, 0, 0);
}

// pack 4 floats -> 4 fp8 e4m3 bytes (OCP on gfx950)
__device__ __forceinline__ int pack4_fp8(float a, float b, float c, float d) {
  int r = __builtin_amdgcn_cvt_pk_fp8_f32(a, b, 0, false);
  r = __builtin_amdgcn_cvt_pk_fp8_f32(c, d, r, true);
  return r;
}

// ---- K1: W1 fp32 [k][j] -> fp8 W1T blocked  +  tvec[k] += W1[k][:] . center ----
__global__ __launch_bounds__(256) void prep_w1(const float* __restrict__ W1,
                                               const float* __restrict__ lb0,
                                               const float* __restrict__ ub0,
                                               unsigned char* __restrict__ W1T,
                                               float* __restrict__ tvec) {
  __shared__ float tile[64 * 65];
  __shared__ float tdot[64];
  const int t = threadIdx.x;
  const int j0 = blockIdx.x * 64, k0 = blockIdx.y * 64;
#pragma unroll
  for (int s = 0; s < 4; ++s) {
    int ck = s * 256 + t;
    int row = ck >> 4;             // k_local 0..63
    int col = (ck & 15) * 4;       // j_local
    float4 v = *(const float4*)(W1 + (size_t)(k0 + row) * N + j0 + col);
    float4 l = *(const float4*)(lb0 + j0 + col);
    float4 u = *(const float4*)(ub0 + j0 + col);
    float part = v.x * 0.5f * (l.x + u.x) + v.y * 0.5f * (l.y + u.y)
               + v.z * 0.5f * (l.z + u.z) + v.w * 0.5f * (l.w + u.w);
    part += __shfl_xor(part, 1, 64);
    part += __shfl_xor(part, 2, 64);
    part += __shfl_xor(part, 4, 64);
    part += __shfl_xor(part, 8, 64);
    if ((t & 15) == 0) tdot[row] = part;   // each row written exactly once
    float* d = &tile[row * 65 + col];
    d[0] = v.x; d[1] = v.y; d[2] = v.z; d[3] = v.w;
  }
  __syncthreads();
  if (t < 64) atomicAdd(&tvec[k0 + t], tdot[t]);
  int jl = t >> 2, ch = (t & 3) * 16;   // 16 consecutive k per thread
  float f[16];
#pragma unroll
  for (int m = 0; m < 16; ++m) f[m] = tile[(ch + m) * 65 + jl] * QSCALE;
  uint4 o;
  o.x = (unsigned)pack4_fp8(f[0], f[1], f[2], f[3]);
  o.y = (unsigned)pack4_fp8(f[4], f[5], f[6], f[7]);
  o.z = (unsigned)pack4_fp8(f[8], f[9], f[10], f[11]);
  o.w = (unsigned)pack4_fp8(f[12], f[13], f[14], f[15]);
  int j = j0 + jl;
  int kb = k0 + ch;                     // k byte index
  *(uint4*)(W1T + (size_t)(j >> 7) * TILE_BYTES + (size_t)(kb >> 7) * KT_BYTES
            + (size_t)((kb >> 4) & 7) * 2048 + (j & 127) * 16) = o;
}

// ---- K2: W2 -> fp8 blocked.  Coalescing fixed: lanes along k (512 B
// contiguous per row), dots via 32-lane shfl reduce, fp8 transpose through
// padded LDS, coalesced uint4 panel writes. ----
__global__ __launch_bounds__(256) void convert_w2(const float* __restrict__ W2,
                                                  const float* __restrict__ b1,
                                                  const float* __restrict__ tvec,
                                                  unsigned char* __restrict__ W2q,
                                                  float* __restrict__ cvec,
                                                  float* __restrict__ Sc) {
  __shared__ int lpack[128][33];          // +1 pad: conflict-free transpose
  const int t = threadIdx.x;
  const int i0 = blockIdx.y * 128;        // row tile
  const int k0 = blockIdx.x * 128;        // k panel
  const int kl = (t & 31) * 4;            // k offset within panel (floats)
  const int rsub = t >> 5;                // 0..7: row sub-index
  float4 bv = *(const float4*)(b1 + k0 + kl);
  float4 tv = *(const float4*)(tvec + k0 + kl);
#pragma unroll
  for (int s = 0; s < 16; ++s) {
    int row = s * 8 + rsub;
    float4 w = *(const float4*)(W2 + (size_t)(i0 + row) * N + k0 + kl);
    float db = w.x * bv.x + w.y * bv.y + w.z * bv.z + w.w * bv.w;
    float dt = w.x * tv.x + w.y * tv.y + w.z * tv.z + w.w * tv.w;
    db += __shfl_xor(db, 1, 64);  dt += __shfl_xor(dt, 1, 64);
    db += __shfl_xor(db, 2, 64);  dt += __shfl_xor(dt, 2, 64);
    db += __shfl_xor(db, 4, 64);  dt += __shfl_xor(dt, 4, 64);
    db += __shfl_xor(db, 8, 64);  dt += __shfl_xor(dt, 8, 64);
    db += __shfl_xor(db, 16, 64); dt += __shfl_xor(dt, 16, 64);
    if ((t & 31) == 0) {
      atomicAdd(&cvec[i0 + row], db);
      atomicAdd(&Sc[i0 + row], dt);
    }
    lpack[row][t & 31] = pack4_fp8(w.x * QSCALE, w.y * QSCALE,
                                   w.z * QSCALE, w.w * QSCALE);
  }
  __syncthreads();
  unsigned char* panel = W2q + (size_t)blockIdx.y * TILE_BYTES
                       + (size_t)blockIdx.x * KT_BYTES;
#pragma unroll
  for (int q = 0; q < 4; ++q) {
    int cid = q * 256 + t;                // 16-B chunk id 0..1023
    int r = cid & 127, c = cid >> 7;
    uint4 o;
    o.x = (unsigned)lpack[r][4 * c + 0];
    o.y = (unsigned)lpack[r][4 * c + 1];
    o.z = (unsigned)lpack[r][4 * c + 2];
    o.w = (unsigned)lpack[r][4 * c + 3];
    *(uint4*)(panel + (size_t)c * 2048 + r * 16) = o;   // consecutive r -> contiguous
  }
}

// ---- K3: R_i = sum_j |(W2q @ W1Tq^T)_ij| * eps_j  via MX fp8 MFMA 32x32x64 ----
// m201-faithful phase: {asm ds_read x12 (issue pinned); stage g+3; vmcnt(8);
// barrier; lgkmcnt(0)+sched_barrier; setprio(1); 8 MFMA; setprio(0); barrier}.
// Counted vmcnt keeps groups g+2,g+3 in flight across barriers (T3+T4).
#define NT 32   // K tiles of 128 bytes; 64 half-groups
#define DSR(dst, addr, OFF) \
  asm volatile("ds_read_b128 %0, %1 offset:" OFF : "=v"(dst) : "v"(addr))

__global__ __launch_bounds__(512, 2) void gemm_absrow(const unsigned char* __restrict__ A,  // W2q blocked
                                                      const unsigned char* __restrict__ B,  // W1Tq blocked
                                                      const float* __restrict__ lb0,
                                                      const float* __restrict__ ub0,
                                                      float* __restrict__ R_acc) {
  __shared__ __align__(16) unsigned char sm[4 * 32768];   // 4 half-group slots
  const int t = threadIdx.x;                // 0..511
  const int lane = t & 63, w = t >> 6;      // 8 waves
  const int wr = w >> 2, wc = w & 3;        // 2 x 4 wave grid
  const int l31 = lane & 31, half = lane >> 5;

  // bijective XCD swizzle (256 blocks, 256 % 8 == 0)
  const int bid = blockIdx.y * 16 + blockIdx.x;
  const int swz = (bid & 7) * 32 + (bid >> 3);
  const int bm = swz >> 4, bn = swz & 15;
  const int i0 = bm * 256, j0 = bn * 256;

  const unsigned char* gA0 = A + (size_t)(2 * bm) * TILE_BYTES + t * 16;
  const unsigned char* gA1 = gA0 + TILE_BYTES;
  const unsigned char* gB0 = B + (size_t)(2 * bn) * TILE_BYTES + t * 16;
  const unsigned char* gB1 = gB0 + TILE_BYTES;

  f32x16 acc[4][2] = {};
  const int sc1 = 0x7F7F7F7F;  // E8M0 scale = 1.0 in all 4 bytes

  const unsigned lds0 =
      (unsigned)(size_t)(__attribute__((address_space(3))) unsigned char*)sm;
  const unsigned aoff = lds0 + wr * 8192 + half * 4096 + l31 * 16;
  const int jb0 = wc * 64 + l31, jb1 = jb0 + 32;
  const unsigned boff0 = lds0 + 16384 + (jb0 >> 7) * 8192 + half * 4096 + (jb0 & 127) * 16;
  const unsigned boff1 = lds0 + 16384 + (jb1 >> 7) * 8192 + half * 4096 + (jb1 & 127) * 16;

  // stage half-group g (tile g>>1, half g&1) into slot g&3
  auto stage = [&](int g) {
    unsigned char* d = sm + (size_t)(g & 3) * 32768 + t * 16;
    const size_t off = (size_t)(g >> 1) * KT_BYTES + (size_t)(g & 1) * 8192;
    gload16(gA0 + off, d);
    gload16(gA1 + off, d + 8192);
    gload16(gB0 + off, d + 16384);
    gload16(gB1 + off, d + 24576);
  };

  V8 af[4], bf[2];

#define PHASE_LOAD(g)                                                     \
  {                                                                       \
    unsigned sb = (unsigned)((g) & 3) * 32768u;                           \
    unsigned sa = aoff + sb, s0 = boff0 + sb, s1 = boff1 + sb;            \
    DSR(af[0].h[0], sa, "0");    DSR(af[0].h[1], sa, "2048");             \
    DSR(af[1].h[0], sa, "512");  DSR(af[1].h[1], sa, "2560");             \
    DSR(af[2].h[0], sa, "1024"); DSR(af[2].h[1], sa, "3072");             \
    DSR(af[3].h[0], sa, "1536"); DSR(af[3].h[1], sa, "3584");             \
    DSR(bf[0].h[0], s0, "0");    DSR(bf[0].h[1], s0, "2048");             \
    DSR(bf[1].h[0], s1, "0");    DSR(bf[1].h[1], s1, "2048");             \
  }

#define PHASE_MFMA()                                                      \
  asm volatile("s_waitcnt lgkmcnt(0)" ::: "memory");                      \
  __builtin_amdgcn_sched_barrier(0);                                      \
  __builtin_amdgcn_s_setprio(1);                                          \
  _Pragma("unroll") for (int tm = 0; tm < 4; ++tm)                        \
    _Pragma("unroll") for (int tn = 0; tn < 2; ++tn)                      \
      acc[tm][tn] = __builtin_amdgcn_mfma_scale_f32_32x32x64_f8f6f4(      \
          af[tm].v, bf[tn].v, acc[tm][tn], 0, 0, 0, sc1, 0, sc1);         \
  __builtin_amdgcn_s_setprio(0);

  // prologue: stage g0,g1,g2; ensure g0 landed everywhere
  stage(0); stage(1); stage(2);
  asm volatile("s_waitcnt vmcnt(8)" ::: "memory");
  __builtin_amdgcn_s_barrier();

  for (int g = 0; g < 61; ++g) {
    PHASE_LOAD(g);                                     // issue pinned (volatile asm)
    stage(g + 3);                                      // slot freed by bar-close(g-1)
    asm volatile("s_waitcnt vmcnt(8)" ::: "memory");   // g+1 landed; g+2,g+3 in flight
    __builtin_amdgcn_s_barrier();
    PHASE_MFMA();
    __builtin_amdgcn_s_barrier();
  }
  PHASE_LOAD(61);
  asm volatile("s_waitcnt vmcnt(4)" ::: "memory");     // g62 landed
  __builtin_amdgcn_s_barrier();
  PHASE_MFMA();
  __builtin_amdgcn_s_barrier();
  PHASE_LOAD(62);
  asm volatile("s_waitcnt vmcnt(0)" ::: "memory");     // g63 landed
  __builtin_amdgcn_s_barrier();
  PHASE_MFMA();
  __builtin_amdgcn_s_barrier();
  PHASE_LOAD(63);
  PHASE_MFMA();

  // epilogue: eps-weighted row L1 norm. C/D 32x32 layout:
  // col = lane&31, row = (r&3) + 8*(r>>2) + 4*(lane>>5)
  float epsv[2];
#pragma unroll
  for (int tn = 0; tn < 2; ++tn) {
    int j = j0 + wc * 64 + tn * 32 + l31;
    epsv[tn] = 0.5f * (ub0[j] - lb0[j]);
  }
#pragma unroll
  for (int tm = 0; tm < 4; ++tm) {
#pragma unroll
    for (int r = 0; r < 16; ++r) {
      float s = fabsf(acc[tm][0][r]) * epsv[0] + fabsf(acc[tm][1][r]) * epsv[1];
#pragma unroll
      for (int off = 1; off < 32; off <<= 1)   // reduce within each 32-lane half
        s += __shfl_xor(s, off, 64);
      if (l31 == 0) {
        int i = i0 + wr * 128 + tm * 32 + (r & 3) + 8 * (r >> 2) + 4 * half;
        atomicAdd(&R_acc[i], s);
      }
    }
  }
}

// ---- K4: fused zero-fill + DeepPolyReLU patch (single pass over 134 MB) ----
struct ReluVals { float lslope, uslope, uinter; };

__device__ __forceinline__ ReluVals relu_vals(int i,
                                              const float* __restrict__ cvec,
                                              const float* __restrict__ Sc,
                                              const float* __restrict__ b2,
                                              const float* __restrict__ R_acc,
                                              const float* __restrict__ raw_alpha) {
  float mid = Sc[i] + cvec[i] + b2[i];
  float rr = R_acc[i] * INV_QQ;
  float lb = mid - rr;
  float ub = mid + rr;
  float alpha = 1.f / (1.f + expf(-raw_alpha[i]));
  float denom = ub - lb;
  float slope = (denom == 0.f) ? 0.f : ub / denom;
  bool below = ub <= 0.f, above = lb >= 0.f;
  bool crossing = !(below || above);
  float base = above ? 1.f : 0.f;
  ReluVals v;
  v.uslope = crossing ? slope : base;
  v.uinter = crossing ? (1.f - slope) * ub : 0.f;
  float l1 = crossing ? 0.f : base;
  float l2 = crossing ? 1.f : base;
  v.lslope = alpha * l1 + (1.f - alpha) * l2;
  return v;
}

__global__ __launch_bounds__(256) void fill_patch(float4* __restrict__ out, int n4,
                                                  const float* __restrict__ cvec,
                                                  const float* __restrict__ Sc,
                                                  const float* __restrict__ b2,
                                                  const float* __restrict__ R_acc,
                                                  const float* __restrict__ raw_alpha) {
  const size_t NN = (size_t)N * N;
  const size_t d1_end = NN;              // diag(lslope)
  const size_t d2_beg = NN + N;          // diag(uslope) after lintercept zeros
  const size_t d2_end = 2 * NN + N;      // uintercept tail
  int idx = blockIdx.x * 256 + threadIdx.x;
  int stride = gridDim.x * 256;
  for (int i = idx; i < n4; i += stride) {
    size_t e = 4 * (size_t)i;
    float4 v = make_float4(0.f, 0.f, 0.f, 0.f);
    if (e >= d2_end) {
      int b = (int)(e - d2_end);
      v.x = relu_vals(b + 0, cvec, Sc, b2, R_acc, raw_alpha).uinter;
      v.y = relu_vals(b + 1, cvec, Sc, b2, R_acc, raw_alpha).uinter;
      v.z = relu_vals(b + 2, cvec, Sc, b2, R_acc, raw_alpha).uinter;
      v.w = relu_vals(b + 3, cvec, Sc, b2, R_acc, raw_alpha).uinter;
    } else if (e < d1_end) {
      int r = (int)(e >> 12), c = (int)(e & 4095);
      if (r >= c && r < c + 4)
        (&v.x)[r - c] = relu_vals(r, cvec, Sc, b2, R_acc, raw_alpha).lslope;
    } else if (e >= d2_beg) {
      size_t e2 = e - d2_beg;
      int r = (int)(e2 >> 12), c = (int)(e2 & 4095);
      if (r >= c && r < c + 4)
        (&v.x)[r - c] = relu_vals(r, cvec, Sc, b2, R_acc, raw_alpha).uslope;
    }
    f32x4 vv = {v.x, v.y, v.z, v.w};                     // streaming store: skip L2
    __builtin_nontemporal_store(vv, (f32x4*)(out + i));
  }
}

extern "C" void kernel_launch(void* const* d_in, const int* in_sizes, int n_in,
                              void* d_out, int out_size, void* d_ws, size_t ws_size,
                              hipStream_t stream) {
  const float* raw_alpha = (const float*)d_in[0];
  const float* lb0 = (const float*)d_in[1];
  const float* ub0 = (const float*)d_in[2];
  const float* W1 = (const float*)d_in[3];
  const float* b1 = (const float*)d_in[4];
  const float* W2 = (const float*)d_in[5];
  const float* b2 = (const float*)d_in[6];

  float* tvec = (float*)d_ws;        // [N]  W1 @ center         (atomic-accum)
  float* cvec = tvec + N;            // [N]  b1 @ W2^T           (atomic-accum)
  float* Sc = cvec + N;              // [N]  W2 @ tvec           (atomic-accum)
  float* R_acc = Sc + N;             // [N]  eps-weighted row L1 (atomic-accum)

  // d_out (134 MB) doubles as fp8 blocked scratch until the final fill
  unsigned char* W2q = (unsigned char*)d_out;        // [N*N] fp8 blocked, 16 MB
  unsigned char* W1Tq = W2q + (size_t)N * N;         // [N*N] fp8 blocked, 16 MB

  (void)hipMemsetAsync(d_ws, 0, 4 * N * sizeof(float), stream);
  prep_w1<<<dim3(N / 64, N / 64), 256, 0, stream>>>(W1, lb0, ub0, W1Tq, tvec);
  convert_w2<<<dim3(N / 128, N / 128), 256, 0, stream>>>(W2, b1, tvec, W2q, cvec, Sc);
  gemm_absrow<<<dim3(16, 16), 512, 0, stream>>>(W2q, W1Tq, lb0, ub0, R_acc);
  int n4 = out_size / 4;
  fill_patch<<<8192, 256, 0, stream>>>((float4*)d_out, n4, cvec, Sc, b2, R_acc, raw_alpha);
}

// Round 3
// 338.039 us; speedup vs baseline: 1.0638x; 1.0487x over previous
//
#include <hip/hip_runtime.h>
#include <stdint.h>

#define N 4096

// blocked scratch layout: addr = tile*524288 + kt*16384 + c*2048 + r*16
//   tile = row>>7, r = row&127, kt = kbyte>>7, c = (kbyte>>4)&7
#define TILE_BYTES 524288   // 128 rows * 4096 B
#define KT_BYTES   16384    // 8 chunks * 128 rows * 16 B

#define QSCALE 256.0f            // W -> fp8 software scale (per tensor)
#define INV_QQ (1.0f / 65536.0f) // undo QSCALE^2 on S

typedef int v8i __attribute__((ext_vector_type(8)));
typedef float f32x16 __attribute__((ext_vector_type(16)));
typedef unsigned int u32x4 __attribute__((ext_vector_type(4)));

union V8 { v8i v; u32x4 h[2]; };

__device__ __forceinline__ void gload16(const unsigned char* g, unsigned char* l) {
  __builtin_amdgcn_global_load_lds(
      (const __attribute__((address_space(1))) unsigned int*)g,
      (__attribute__((address_space(3))) unsigned int*)l, 16, 0, 0);
}

// pack 4 floats -> 4 fp8 e4m3 bytes (OCP on gfx950)
__device__ __forceinline__ int pack4_fp8(float a, float b, float c, float d) {
  int r = __builtin_amdgcn_cvt_pk_fp8_f32(a, b, 0, false);
  r = __builtin_amdgcn_cvt_pk_fp8_f32(c, d, r, true);
  return r;
}

// ---- K1: W1 fp32 [k][j] -> fp8 W1T blocked  +  tvec[k] += W1[k][:] . center ----
__global__ __launch_bounds__(256) void prep_w1(const float* __restrict__ W1,
                                               const float* __restrict__ lb0,
                                               const float* __restrict__ ub0,
                                               unsigned char* __restrict__ W1T,
                                               float* __restrict__ tvec) {
  __shared__ float tile[64 * 65];
  __shared__ float tdot[64];
  const int t = threadIdx.x;
  const int j0 = blockIdx.x * 64, k0 = blockIdx.y * 64;
#pragma unroll
  for (int s = 0; s < 4; ++s) {
    int ck = s * 256 + t;
    int row = ck >> 4;             // k_local 0..63
    int col = (ck & 15) * 4;       // j_local
    float4 v = *(const float4*)(W1 + (size_t)(k0 + row) * N + j0 + col);
    float4 l = *(const float4*)(lb0 + j0 + col);
    float4 u = *(const float4*)(ub0 + j0 + col);
    float part = v.x * 0.5f * (l.x + u.x) + v.y * 0.5f * (l.y + u.y)
               + v.z * 0.5f * (l.z + u.z) + v.w * 0.5f * (l.w + u.w);
    part += __shfl_xor(part, 1, 64);
    part += __shfl_xor(part, 2, 64);
    part += __shfl_xor(part, 4, 64);
    part += __shfl_xor(part, 8, 64);
    if ((t & 15) == 0) tdot[row] = part;   // each row written exactly once
    float* d = &tile[row * 65 + col];
    d[0] = v.x; d[1] = v.y; d[2] = v.z; d[3] = v.w;
  }
  __syncthreads();
  if (t < 64) atomicAdd(&tvec[k0 + t], tdot[t]);
  int jl = t >> 2, ch = (t & 3) * 16;   // 16 consecutive k per thread
  float f[16];
#pragma unroll
  for (int m = 0; m < 16; ++m) f[m] = tile[(ch + m) * 65 + jl] * QSCALE;
  uint4 o;
  o.x = (unsigned)pack4_fp8(f[0], f[1], f[2], f[3]);
  o.y = (unsigned)pack4_fp8(f[4], f[5], f[6], f[7]);
  o.z = (unsigned)pack4_fp8(f[8], f[9], f[10], f[11]);
  o.w = (unsigned)pack4_fp8(f[12], f[13], f[14], f[15]);
  int j = j0 + jl;
  int kb = k0 + ch;                     // k byte index
  *(uint4*)(W1T + (size_t)(j >> 7) * TILE_BYTES + (size_t)(kb >> 7) * KT_BYTES
            + (size_t)((kb >> 4) & 7) * 2048 + (j & 127) * 16) = o;
}

// ---- K2: W2 -> fp8 blocked, coalesced loads along k, shfl-reduced dots ----
__global__ __launch_bounds__(256) void convert_w2(const float* __restrict__ W2,
                                                  const float* __restrict__ b1,
                                                  const float* __restrict__ tvec,
                                                  unsigned char* __restrict__ W2q,
                                                  float* __restrict__ cvec,
                                                  float* __restrict__ Sc) {
  __shared__ int lpack[128][33];          // +1 pad: conflict-free transpose
  const int t = threadIdx.x;
  const int i0 = blockIdx.y * 128;        // row tile
  const int k0 = blockIdx.x * 128;        // k panel
  const int kl = (t & 31) * 4;            // k offset within panel (floats)
  const int rsub = t >> 5;                // 0..7: row sub-index
  float4 bv = *(const float4*)(b1 + k0 + kl);
  float4 tv = *(const float4*)(tvec + k0 + kl);
#pragma unroll
  for (int s = 0; s < 16; ++s) {
    int row = s * 8 + rsub;
    float4 w = *(const float4*)(W2 + (size_t)(i0 + row) * N + k0 + kl);
    float db = w.x * bv.x + w.y * bv.y + w.z * bv.z + w.w * bv.w;
    float dt = w.x * tv.x + w.y * tv.y + w.z * tv.z + w.w * tv.w;
    db += __shfl_xor(db, 1, 64);  dt += __shfl_xor(dt, 1, 64);
    db += __shfl_xor(db, 2, 64);  dt += __shfl_xor(dt, 2, 64);
    db += __shfl_xor(db, 4, 64);  dt += __shfl_xor(dt, 4, 64);
    db += __shfl_xor(db, 8, 64);  dt += __shfl_xor(dt, 8, 64);
    db += __shfl_xor(db, 16, 64); dt += __shfl_xor(dt, 16, 64);
    if ((t & 31) == 0) {
      atomicAdd(&cvec[i0 + row], db);
      atomicAdd(&Sc[i0 + row], dt);
    }
    lpack[row][t & 31] = pack4_fp8(w.x * QSCALE, w.y * QSCALE,
                                   w.z * QSCALE, w.w * QSCALE);
  }
  __syncthreads();
  unsigned char* panel = W2q + (size_t)blockIdx.y * TILE_BYTES
                       + (size_t)blockIdx.x * KT_BYTES;
#pragma unroll
  for (int q = 0; q < 4; ++q) {
    int cid = q * 256 + t;                // 16-B chunk id 0..1023
    int r = cid & 127, c = cid >> 7;
    uint4 o;
    o.x = (unsigned)lpack[r][4 * c + 0];
    o.y = (unsigned)lpack[r][4 * c + 1];
    o.z = (unsigned)lpack[r][4 * c + 2];
    o.w = (unsigned)lpack[r][4 * c + 3];
    *(uint4*)(panel + (size_t)c * 2048 + r * 16) = o;   // consecutive r -> contiguous
  }
}

// ---- K3: R_i = sum_j |(W2q @ W1Tq^T)_ij| * eps_j  via MX fp8 MFMA 32x32x64 ----
// Counted-lgkmcnt interleave: reads issued (af0,bf0,bf1,af1,af2,af3), each
// MFMA pair fires at lgkmcnt(6/4/2/0) + sched_barrier(0) (rule #18).  One
// barrier per phase; stage AFTER barrier keeps slot hazard safe (prior
// phase's lgkmcnt(0) precedes each wave's barrier arrival).  vmcnt(8)
// counted: groups g+1,g+2 stay in flight across barriers (T3+T4).
#define DSR(dst, addr, OFF) \
  asm volatile("ds_read_b128 %0, %1 offset:" OFF : "=v"(dst) : "v"(addr))

__global__ __launch_bounds__(512, 2) void gemm_absrow(const unsigned char* __restrict__ A,  // W2q blocked
                                                      const unsigned char* __restrict__ B,  // W1Tq blocked
                                                      const float* __restrict__ lb0,
                                                      const float* __restrict__ ub0,
                                                      float* __restrict__ R_acc) {
  __shared__ __align__(16) unsigned char sm[4 * 32768];   // 4 half-group slots
  const int t = threadIdx.x;                // 0..511
  const int lane = t & 63, w = t >> 6;      // 8 waves
  const int wr = w >> 2, wc = w & 3;        // 2 x 4 wave grid
  const int l31 = lane & 31, half = lane >> 5;

  // bijective XCD swizzle (256 blocks, 256 % 8 == 0)
  const int bid = blockIdx.y * 16 + blockIdx.x;
  const int swz = (bid & 7) * 32 + (bid >> 3);
  const int bm = swz >> 4, bn = swz & 15;
  const int i0 = bm * 256, j0 = bn * 256;

  const unsigned char* gA0 = A + (size_t)(2 * bm) * TILE_BYTES + t * 16;
  const unsigned char* gA1 = gA0 + TILE_BYTES;
  const unsigned char* gB0 = B + (size_t)(2 * bn) * TILE_BYTES + t * 16;
  const unsigned char* gB1 = gB0 + TILE_BYTES;

  f32x16 acc[4][2] = {};
  const int sc1 = 0x7F7F7F7F;  // E8M0 scale = 1.0 in all 4 bytes

  const unsigned lds0 =
      (unsigned)(size_t)(__attribute__((address_space(3))) unsigned char*)sm;
  const unsigned aoff = lds0 + wr * 8192 + half * 4096 + l31 * 16;
  const int jb0 = wc * 64 + l31, jb1 = jb0 + 32;
  const unsigned boff0 = lds0 + 16384 + (jb0 >> 7) * 8192 + half * 4096 + (jb0 & 127) * 16;
  const unsigned boff1 = lds0 + 16384 + (jb1 >> 7) * 8192 + half * 4096 + (jb1 & 127) * 16;

  // stage half-group g (tile g>>1, half g&1) into slot g&3
  auto stage = [&](int g) {
    unsigned char* d = sm + (size_t)(g & 3) * 32768 + t * 16;
    const size_t off = (size_t)(g >> 1) * KT_BYTES + (size_t)(g & 1) * 8192;
    gload16(gA0 + off, d);
    gload16(gA1 + off, d + 8192);
    gload16(gB0 + off, d + 16384);
    gload16(gB1 + off, d + 24576);
  };

  V8 af[4], bf[2];

  // issue order matters: af0, bf0, bf1, af1, af2, af3 (pairs of b128)
#define PHASE_LOAD(g)                                                     \
  {                                                                       \
    unsigned sb = (unsigned)((g) & 3) * 32768u;                           \
    unsigned sa = aoff + sb, s0 = boff0 + sb, s1 = boff1 + sb;            \
    DSR(af[0].h[0], sa, "0");    DSR(af[0].h[1], sa, "2048");             \
    DSR(bf[0].h[0], s0, "0");    DSR(bf[0].h[1], s0, "2048");             \
    DSR(bf[1].h[0], s1, "0");    DSR(bf[1].h[1], s1, "2048");             \
    DSR(af[1].h[0], sa, "512");  DSR(af[1].h[1], sa, "2560");             \
    DSR(af[2].h[0], sa, "1024"); DSR(af[2].h[1], sa, "3072");             \
    DSR(af[3].h[0], sa, "1536"); DSR(af[3].h[1], sa, "3584");             \
  }

#define MFMA2(tm)                                                         \
  acc[tm][0] = __builtin_amdgcn_mfma_scale_f32_32x32x64_f8f6f4(           \
      af[tm].v, bf[0].v, acc[tm][0], 0, 0, 0, sc1, 0, sc1);               \
  acc[tm][1] = __builtin_amdgcn_mfma_scale_f32_32x32x64_f8f6f4(           \
      af[tm].v, bf[1].v, acc[tm][1], 0, 0, 0, sc1, 0, sc1);

#define PHASE_MFMA()                                                      \
  __builtin_amdgcn_s_setprio(1);                                          \
  asm volatile("s_waitcnt lgkmcnt(6)" ::: "memory");                      \
  __builtin_amdgcn_sched_barrier(0);                                      \
  MFMA2(0)                                                                \
  asm volatile("s_waitcnt lgkmcnt(4)" ::: "memory");                      \
  __builtin_amdgcn_sched_barrier(0);                                      \
  MFMA2(1)                                                                \
  asm volatile("s_waitcnt lgkmcnt(2)" ::: "memory");                      \
  __builtin_amdgcn_sched_barrier(0);                                      \
  MFMA2(2)                                                                \
  asm volatile("s_waitcnt lgkmcnt(0)" ::: "memory");                      \
  __builtin_amdgcn_sched_barrier(0);                                      \
  MFMA2(3)                                                                \
  __builtin_amdgcn_s_setprio(0);

  // prologue: stage half-groups 0,1,2 (12 loads in flight)
  stage(0); stage(1); stage(2);

#pragma unroll 1
  for (int g = 0; g < 61; ++g) {
    asm volatile("s_waitcnt vmcnt(8)" ::: "memory");   // group g landed
    __builtin_amdgcn_s_barrier();                      // ... in all waves
    PHASE_LOAD(g);
    stage(g + 3);                                      // slot (g-1)&3: reads done pre-barrier
    PHASE_MFMA();
  }
  asm volatile("s_waitcnt vmcnt(8)" ::: "memory");     // g=61 landed (62,63 in flight)
  __builtin_amdgcn_s_barrier();
  PHASE_LOAD(61);
  PHASE_MFMA();
  asm volatile("s_waitcnt vmcnt(4)" ::: "memory");     // g=62 landed
  __builtin_amdgcn_s_barrier();
  PHASE_LOAD(62);
  PHASE_MFMA();
  asm volatile("s_waitcnt vmcnt(0)" ::: "memory");     // g=63 landed
  __builtin_amdgcn_s_barrier();
  PHASE_LOAD(63);
  PHASE_MFMA();

  // epilogue: eps-weighted row L1 norm. C/D 32x32 layout:
  // col = lane&31, row = (r&3) + 8*(r>>2) + 4*(lane>>5)
  float epsv[2];
#pragma unroll
  for (int tn = 0; tn < 2; ++tn) {
    int j = j0 + wc * 64 + tn * 32 + l31;
    epsv[tn] = 0.5f * (ub0[j] - lb0[j]);
  }
#pragma unroll
  for (int tm = 0; tm < 4; ++tm) {
#pragma unroll
    for (int r = 0; r < 16; ++r) {
      float s = fabsf(acc[tm][0][r]) * epsv[0] + fabsf(acc[tm][1][r]) * epsv[1];
#pragma unroll
      for (int off = 1; off < 32; off <<= 1)   // reduce within each 32-lane half
        s += __shfl_xor(s, off, 64);
      if (l31 == 0) {
        int i = i0 + wr * 128 + tm * 32 + (r & 3) + 8 * (r >> 2) + 4 * half;
        atomicAdd(&R_acc[i], s);
      }
    }
  }
}

// ---- K4: sparse DeepPolyReLU patch after bulk hipMemsetAsync zero-fill ----
struct ReluVals { float lslope, uslope, uinter; };

__device__ __forceinline__ ReluVals relu_vals(int i,
                                              const float* __restrict__ cvec,
                                              const float* __restrict__ Sc,
                                              const float* __restrict__ b2,
                                              const float* __restrict__ R_acc,
                                              const float* __restrict__ raw_alpha) {
  float mid = Sc[i] + cvec[i] + b2[i];
  float rr = R_acc[i] * INV_QQ;
  float lb = mid - rr;
  float ub = mid + rr;
  float alpha = 1.f / (1.f + expf(-raw_alpha[i]));
  float denom = ub - lb;
  float slope = (denom == 0.f) ? 0.f : ub / denom;
  bool below = ub <= 0.f, above = lb >= 0.f;
  bool crossing = !(below || above);
  float base = above ? 1.f : 0.f;
  ReluVals v;
  v.uslope = crossing ? slope : base;
  v.uinter = crossing ? (1.f - slope) * ub : 0.f;
  float l1 = crossing ? 0.f : base;
  float l2 = crossing ? 1.f : base;
  v.lslope = alpha * l1 + (1.f - alpha) * l2;
  return v;
}

__global__ __launch_bounds__(256) void patch_diag(float* __restrict__ out,
                                                  const float* __restrict__ cvec,
                                                  const float* __restrict__ Sc,
                                                  const float* __restrict__ b2,
                                                  const float* __restrict__ R_acc,
                                                  const float* __restrict__ raw_alpha) {
  const size_t NN = (size_t)N * N;
  int i = blockIdx.x * 256 + threadIdx.x;          // 0..N-1
  ReluVals v = relu_vals(i, cvec, Sc, b2, R_acc, raw_alpha);
  out[(size_t)i * (N + 1)] = v.lslope;             // diag(lslope)
  out[NN + N + (size_t)i * (N + 1)] = v.uslope;    // diag(uslope)
  out[2 * NN + N + i] = v.uinter;                  // uintercept row
}

extern "C" void kernel_launch(void* const* d_in, const int* in_sizes, int n_in,
                              void* d_out, int out_size, void* d_ws, size_t ws_size,
                              hipStream_t stream) {
  const float* raw_alpha = (const float*)d_in[0];
  const float* lb0 = (const float*)d_in[1];
  const float* ub0 = (const float*)d_in[2];
  const float* W1 = (const float*)d_in[3];
  const float* b1 = (const float*)d_in[4];
  const float* W2 = (const float*)d_in[5];
  const float* b2 = (const float*)d_in[6];

  float* tvec = (float*)d_ws;        // [N]  W1 @ center         (atomic-accum)
  float* cvec = tvec + N;            // [N]  b1 @ W2^T           (atomic-accum)
  float* Sc = cvec + N;              // [N]  W2 @ tvec           (atomic-accum)
  float* R_acc = Sc + N;             // [N]  eps-weighted row L1 (atomic-accum)

  // d_out (134 MB) doubles as fp8 blocked scratch until the final fill
  unsigned char* W2q = (unsigned char*)d_out;        // [N*N] fp8 blocked, 16 MB
  unsigned char* W1Tq = W2q + (size_t)N * N;         // [N*N] fp8 blocked, 16 MB

  (void)hipMemsetAsync(d_ws, 0, 4 * N * sizeof(float), stream);
  prep_w1<<<dim3(N / 64, N / 64), 256, 0, stream>>>(W1, lb0, ub0, W1Tq, tvec);
  convert_w2<<<dim3(N / 128, N / 128), 256, 0, stream>>>(W2, b1, tvec, W2q, cvec, Sc);
  gemm_absrow<<<dim3(16, 16), 512, 0, stream>>>(W2q, W1Tq, lb0, ub0, R_acc);
  // bulk zero-fill (peak write BW), then sparse diagonal/vector patch
  (void)hipMemsetAsync(d_out, 0, (size_t)out_size * sizeof(float), stream);
  patch_diag<<<N / 256, 256, 0, stream>>>((float*)d_out, cvec, Sc, b2, R_acc, raw_alpha);
}